// Round 1
// baseline (1070.437 us; speedup 1.0000x reference)
//
#include <hip/hip_runtime.h>
#include <hip/hip_bf16.h>

typedef unsigned short u16;
typedef unsigned int u32;
typedef short v8s __attribute__((ext_vector_type(8)));
typedef float v4f __attribute__((ext_vector_type(4)));

#define NB 16
#define NQ 64
#define NKV 4096
#define QD 768
#define KD 1024
#define NH 12
#define HD 64

__device__ __forceinline__ u16 f2bf(float f) {
  union { float f; u32 u; } c; c.f = f;
  u32 u = c.u;
  u += 0x7FFFu + ((u >> 16) & 1u);  // round-to-nearest-even
  return (u16)(u >> 16);
}
__device__ __forceinline__ u32 pack2(float a, float b) {
  return (u32)f2bf(a) | ((u32)f2bf(b) << 16);
}

// W (K,N) f32 -> WT (N,K) bf16
__global__ void prep_wT(const float* __restrict__ W, u16* __restrict__ WT, int K, int N) {
  int idx = blockIdx.x * 256 + threadIdx.x;
  if (idx >= K * N) return;
  int n = idx / K, k = idx - n * K;
  WT[idx] = f2bf(W[(size_t)k * N + n]);
}

__global__ void conv_bf16(const float* __restrict__ s, u16* __restrict__ d, int n) {
  int i = blockIdx.x * 256 + threadIdx.x;
  if (i < n) d[i] = f2bf(s[i]);
}

__global__ void concat_bias(const float* __restrict__ a, const float* __restrict__ b,
                            float* __restrict__ o) {
  int i = blockIdx.x * 256 + threadIdx.x;
  if (i < 768) o[i] = a[i];
  else if (i < 1536) o[i] = b[i - 768];
}

// C[M,N] = A[M,K] @ BT[N,K]^T + bias[N]
template<bool A_F32, bool OUT_BF16>
__global__ __launch_bounds__(256) void gemm_k(
    const void* __restrict__ Ap, const u16* __restrict__ BT,
    const float* __restrict__ bias, void* __restrict__ Cp,
    int M, int N, int K)
{
  __shared__ __align__(16) u16 As[128][40];  // pad 32->40: 2-way bank aliasing only
  __shared__ __align__(16) u16 Bs[128][40];
  const int bn0 = blockIdx.x * 128, bm0 = blockIdx.y * 128;
  const int t = threadIdx.x, lane = t & 63, wv = t >> 6;
  const int wm = (wv & 1) * 64, wn = (wv >> 1) * 64;
  const int lm = lane & 15, quad = lane >> 4;
  const int sr = t >> 2, sc = (t & 3) * 8;

  v4f zero = {0.f, 0.f, 0.f, 0.f};
  v4f acc[4][4];
#pragma unroll
  for (int i = 0; i < 4; ++i)
#pragma unroll
    for (int j = 0; j < 4; ++j) acc[i][j] = zero;

  for (int k0 = 0; k0 < K; k0 += 32) {
#pragma unroll
    for (int rr = sr; rr < 128; rr += 64) {
      if constexpr (A_F32) {
        const float* A = (const float*)Ap;
        const float* s = A + (size_t)(bm0 + rr) * K + k0 + sc;
        float4 f0 = *(const float4*)s;
        float4 f1 = *(const float4*)(s + 4);
        uint4 w;
        w.x = pack2(f0.x, f0.y); w.y = pack2(f0.z, f0.w);
        w.z = pack2(f1.x, f1.y); w.w = pack2(f1.z, f1.w);
        *(uint4*)&As[rr][sc] = w;
      } else {
        const u16* A = (const u16*)Ap;
        *(uint4*)&As[rr][sc] = *(const uint4*)(A + (size_t)(bm0 + rr) * K + k0 + sc);
      }
      *(uint4*)&Bs[rr][sc] = *(const uint4*)(BT + (size_t)(bn0 + rr) * K + k0 + sc);
    }
    __syncthreads();
    v8s a[4], b[4];
#pragma unroll
    for (int mt = 0; mt < 4; ++mt) a[mt] = *(const v8s*)&As[wm + mt * 16 + lm][quad * 8];
#pragma unroll
    for (int nt = 0; nt < 4; ++nt) b[nt] = *(const v8s*)&Bs[wn + nt * 16 + lm][quad * 8];
#pragma unroll
    for (int mt = 0; mt < 4; ++mt)
#pragma unroll
      for (int nt = 0; nt < 4; ++nt)
        acc[mt][nt] = __builtin_amdgcn_mfma_f32_16x16x32_bf16(a[mt], b[nt], acc[mt][nt], 0, 0, 0);
    __syncthreads();
  }
#pragma unroll
  for (int mt = 0; mt < 4; ++mt)
#pragma unroll
    for (int nt = 0; nt < 4; ++nt)
#pragma unroll
      for (int r = 0; r < 4; ++r) {
        int row = bm0 + wm + mt * 16 + quad * 4 + r;  // C/D: row=quad*4+reg (m89)
        int col = bn0 + wn + nt * 16 + lm;            //      col=lane&15
        float v = acc[mt][nt][r] + bias[col];
        if constexpr (OUT_BF16) ((u16*)Cp)[(size_t)row * N + col] = f2bf(v);
        else                    ((float*)Cp)[(size_t)row * N + col] = v;
      }
}

__device__ __forceinline__ void wr8(u16 (*Vsw)[40], int dh, int jl, uint4 v) {
  Vsw[dh + 0][jl] = (u16)v.x; Vsw[dh + 1][jl] = (u16)(v.x >> 16);
  Vsw[dh + 2][jl] = (u16)v.y; Vsw[dh + 3][jl] = (u16)(v.y >> 16);
  Vsw[dh + 4][jl] = (u16)v.z; Vsw[dh + 5][jl] = (u16)(v.z >> 16);
  Vsw[dh + 6][jl] = (u16)v.w; Vsw[dh + 7][jl] = (u16)(v.w >> 16);
}

// one block per (b,h); wave w owns q-rows w*16..w*16+15, streams all kv
__global__ __launch_bounds__(256) void attn_k(
    const u16* __restrict__ qp,   // (B*64, 768) bf16
    const u16* __restrict__ kvp,  // (B*4096, 1536) bf16: k at col h*64, v at 768+h*64
    u16* __restrict__ xo)         // (B*64, 768) bf16
{
  __shared__ __align__(16) u16 qs[64][72];
  __shared__ __align__(16) u16 Ps[4][16][40];
  __shared__ __align__(16) u16 Vs[4][64][40];
  const int bh = blockIdx.x, b = bh / NH, h = bh - b * NH;
  const int t = threadIdx.x, lane = t & 63, w = t >> 6;
  const int lm = lane & 15, quad = lane >> 4;

  {
    int r = t >> 2, c = (t & 3) * 16;
    const u16* src = qp + (size_t)(b * NQ + r) * QD + h * HD + c;
    *(uint4*)&qs[r][c] = *(const uint4*)src;
    *(uint4*)&qs[r][c + 8] = *(const uint4*)(src + 8);
  }
  __syncthreads();
  v8s aq0 = *(const v8s*)&qs[w * 16 + lm][quad * 8];
  v8s aq1 = *(const v8s*)&qs[w * 16 + lm][32 + quad * 8];

  float mst[4], lst[4];
  v4f O[4];
  v4f zero = {0.f, 0.f, 0.f, 0.f};
#pragma unroll
  for (int r = 0; r < 4; ++r) { mst[r] = -INFINITY; lst[r] = 0.f; }
#pragma unroll
  for (int d = 0; d < 4; ++d) O[d] = zero;

  const float scale = 0.125f;  // 1/sqrt(64)
  const size_t brow = (size_t)b * NKV;
  const u16* kb = kvp + h * HD;
  const u16* vb = kvp + QD + h * HD;

  for (int j0 = 0; j0 < NKV; j0 += 32) {
    const u16* k0p = kb + (brow + j0 + lm) * 1536 + quad * 8;
    const u16* k1p = kb + (brow + j0 + 16 + lm) * 1536 + quad * 8;
    v8s bk00 = *(const v8s*)k0p;
    v8s bk01 = *(const v8s*)(k0p + 32);
    v8s bk10 = *(const v8s*)k1p;
    v8s bk11 = *(const v8s*)(k1p + 32);

    v4f S0 = zero, S1 = zero;
    S0 = __builtin_amdgcn_mfma_f32_16x16x32_bf16(aq0, bk00, S0, 0, 0, 0);
    S0 = __builtin_amdgcn_mfma_f32_16x16x32_bf16(aq1, bk01, S0, 0, 0, 0);
    S1 = __builtin_amdgcn_mfma_f32_16x16x32_bf16(aq0, bk10, S1, 0, 0, 0);
    S1 = __builtin_amdgcn_mfma_f32_16x16x32_bf16(aq1, bk11, S1, 0, 0, 0);

    float p0[4], p1[4], rmax[4];
#pragma unroll
    for (int r = 0; r < 4; ++r) {
      p0[r] = S0[r] * scale; p1[r] = S1[r] * scale;
      rmax[r] = fmaxf(p0[r], p1[r]);
    }
#pragma unroll
    for (int off = 1; off <= 8; off <<= 1)
#pragma unroll
      for (int r = 0; r < 4; ++r) rmax[r] = fmaxf(rmax[r], __shfl_xor(rmax[r], off, 64));

    float alpha[4], rsum[4];
#pragma unroll
    for (int r = 0; r < 4; ++r) {
      float mn = fmaxf(mst[r], rmax[r]);
      alpha[r] = __expf(mst[r] - mn);
      p0[r] = __expf(p0[r] - mn);
      p1[r] = __expf(p1[r] - mn);
      mst[r] = mn;
      rsum[r] = p0[r] + p1[r];
    }
#pragma unroll
    for (int off = 1; off <= 8; off <<= 1)
#pragma unroll
      for (int r = 0; r < 4; ++r) rsum[r] += __shfl_xor(rsum[r], off, 64);
#pragma unroll
    for (int r = 0; r < 4; ++r) lst[r] = lst[r] * alpha[r] + rsum[r];

    // P: C-layout -> A-layout via per-wave LDS round-trip (m120 pattern)
#pragma unroll
    for (int r = 0; r < 4; ++r) {
      Ps[w][quad * 4 + r][lm] = f2bf(p0[r]);
      Ps[w][quad * 4 + r][16 + lm] = f2bf(p1[r]);
    }
    // V chunk transposed into per-wave LDS: Vs[d][j]
    {
      int jl = lane & 31, dh = (lane >> 5) * 32;
      const u16* vs = vb + (brow + j0 + jl) * 1536 + dh;
      uint4 v0 = *(const uint4*)vs;
      uint4 v1 = *(const uint4*)(vs + 8);
      uint4 v2 = *(const uint4*)(vs + 16);
      uint4 v3 = *(const uint4*)(vs + 24);
      wr8(Vs[w], dh + 0, jl, v0);
      wr8(Vs[w], dh + 8, jl, v1);
      wr8(Vs[w], dh + 16, jl, v2);
      wr8(Vs[w], dh + 24, jl, v3);
    }
#pragma unroll
    for (int d = 0; d < 4; ++d)
#pragma unroll
      for (int r = 0; r < 4; ++r) O[d][r] *= alpha[r];

    v8s aP = *(const v8s*)&Ps[w][lm][quad * 8];
#pragma unroll
    for (int d = 0; d < 4; ++d) {
      v8s bV = *(const v8s*)&Vs[w][d * 16 + lm][quad * 8];
      O[d] = __builtin_amdgcn_mfma_f32_16x16x32_bf16(aP, bV, O[d], 0, 0, 0);
    }
  }
#pragma unroll
  for (int r = 0; r < 4; ++r) lst[r] = 1.f / lst[r];
#pragma unroll
  for (int d = 0; d < 4; ++d)
#pragma unroll
    for (int r = 0; r < 4; ++r) {
      int row = b * NQ + w * 16 + quad * 4 + r;
      xo[(size_t)row * QD + h * HD + d * 16 + lm] = f2bf(O[d][r] * lst[r]);
    }
}

extern "C" void kernel_launch(void* const* d_in, const int* in_sizes, int n_in,
                              void* d_out, int out_size, void* d_ws, size_t ws_size,
                              hipStream_t stream) {
  const float* query = (const float*)d_in[0];
  const float* kv    = (const float*)d_in[1];
  const float* Wq    = (const float*)d_in[2];
  const float* bq    = (const float*)d_in[3];
  const float* Wk    = (const float*)d_in[4];
  const float* bk    = (const float*)d_in[5];
  const float* Wv    = (const float*)d_in[6];
  const float* bv    = (const float*)d_in[7];
  const float* Wo    = (const float*)d_in[8];
  const float* bo    = (const float*)d_in[9];
  float* out = (float*)d_out;
  char* ws = (char*)d_ws;

  // ws layout (bytes, 16-aligned):
  u16*   WkvT = (u16*)(ws);                  // (1536,1024) bf16   3,145,728
  float* bkv  = (float*)(ws + 3145728);      // 1536 f32           6,144
  u16*   WqT  = (u16*)(ws + 3151872);        // (768,768)          1,179,648
  u16*   WoT  = (u16*)(ws + 4331520);        //                    1,179,648
  u16*   qbf  = (u16*)(ws + 5511168);        // (1024,768)         1,572,864
  u16*   qp   = (u16*)(ws + 7084032);        // (1024,768)         1,572,864
  u16*   xov  = (u16*)(ws + 8656896);        // (1024,768)         1,572,864
  u16*   kvp  = (u16*)(ws + 10229760);       // (65536,1536)       201,326,592
  // total: 211,556,352 bytes

  prep_wT<<<3072, 256, 0, stream>>>(Wk, WkvT, KD, QD);
  prep_wT<<<3072, 256, 0, stream>>>(Wv, WkvT + 768 * 1024, KD, QD);
  prep_wT<<<2304, 256, 0, stream>>>(Wq, WqT, QD, QD);
  prep_wT<<<2304, 256, 0, stream>>>(Wo, WoT, QD, QD);
  conv_bf16<<<3072, 256, 0, stream>>>(query, qbf, NB * NQ * QD);
  concat_bias<<<6, 256, 0, stream>>>(bk, bv, bkv);

  // q projection: (1024,768) @ (768,768)
  gemm_k<false, true><<<dim3(6, 8), 256, 0, stream>>>(qbf, WqT, bq, qp, 1024, QD, QD);
  // fused k+v projection: (65536,1024) @ (1024,1536), reads kv f32 once
  gemm_k<true, true><<<dim3(12, 512), 256, 0, stream>>>(kv, WkvT, bkv, kvp, 65536, 1536, KD);
  // attention
  attn_k<<<NB * NH, 256, 0, stream>>>(qp, kvp, xov);
  // output projection -> f32
  gemm_k<false, false><<<dim3(6, 8), 256, 0, stream>>>(xov, WoT, bo, out, 1024, QD, QD);
}

// Round 2
// 1046.734 us; speedup vs baseline: 1.0226x; 1.0226x over previous
//
#include <hip/hip_runtime.h>
#include <hip/hip_bf16.h>

typedef unsigned short u16;
typedef unsigned int u32;
typedef short v8s __attribute__((ext_vector_type(8)));
typedef float v4f __attribute__((ext_vector_type(4)));

#define NB 16
#define NQ 64
#define NKV 4096
#define QD 768
#define KD 1024
#define NH 12
#define HD 64

__device__ __forceinline__ u16 f2bf(float f) {
  union { float f; u32 u; } c; c.f = f;
  u32 u = c.u;
  u += 0x7FFFu + ((u >> 16) & 1u);  // round-to-nearest-even
  return (u16)(u >> 16);
}
__device__ __forceinline__ u32 pack2(float a, float b) {
  return (u32)f2bf(a) | ((u32)f2bf(b) << 16);
}

// async 16B global->LDS; lds dest must be wave-uniform base (+lane*16 implicit)
__device__ __forceinline__ void async16(const void* g, void* l) {
  __builtin_amdgcn_global_load_lds(
      (const __attribute__((address_space(1))) void*)g,
      (__attribute__((address_space(3))) void*)l, 16, 0, 0);
}

// W (K,N) f32 -> WT (N,K) bf16, coalesced both sides via LDS tile
__global__ __launch_bounds__(256) void prep_wT2(const float* __restrict__ W,
                                                u16* __restrict__ WT, int K, int N) {
  __shared__ float tile[32][33];
  const int n0 = blockIdx.x * 32, k0 = blockIdx.y * 32;
  const int tr = threadIdx.x >> 5, tc = threadIdx.x & 31;
#pragma unroll
  for (int r = tr; r < 32; r += 8) tile[r][tc] = W[(size_t)(k0 + r) * N + n0 + tc];
  __syncthreads();
#pragma unroll
  for (int r = tr; r < 32; r += 8) WT[(size_t)(n0 + r) * K + k0 + tc] = f2bf(tile[tc][r]);
}

// f32 -> bf16, 8 elements/thread, grid must exactly cover n/8
__global__ __launch_bounds__(256) void conv8(const float* __restrict__ s,
                                             u16* __restrict__ d, int n8) {
  int i = blockIdx.x * 256 + threadIdx.x;
  if (i >= n8) return;
  const float4* sp = (const float4*)s + (size_t)i * 2;
  float4 a = sp[0], b = sp[1];
  uint4 o;
  o.x = pack2(a.x, a.y); o.y = pack2(a.z, a.w);
  o.z = pack2(b.x, b.y); o.w = pack2(b.z, b.w);
  ((uint4*)d)[i] = o;
}

__global__ void concat_bias(const float* __restrict__ a, const float* __restrict__ b,
                            float* __restrict__ o) {
  int i = blockIdx.x * 256 + threadIdx.x;
  if (i < 768) o[i] = a[i];
  else if (i < 1536) o[i] = b[i - 768];
}

// C = A[M,K](bf16) @ BT[N,K]^T + bias.
// KV_SPLIT: cols<768 -> kp[grow*768+col] bf16; cols>=768 -> vT[(b*768+cv)*4096+kvr] bf16 (transposed)
template<bool OUT_BF16, bool KV_SPLIT>
__global__ __launch_bounds__(256) void gemm_a(
    const u16* __restrict__ A, const u16* __restrict__ BT,
    const float* __restrict__ bias, void* __restrict__ Cp, u16* __restrict__ Vtp,
    int M, int N, int K, int m_off)
{
  __shared__ __align__(16) u16 As[128][32];  // unpadded: required by global_load_lds
  __shared__ __align__(16) u16 Bs[128][32];
  const int bn0 = blockIdx.x * 128, bm0 = blockIdx.y * 128;
  const int t = threadIdx.x, lane = t & 63, wv = t >> 6;
  const int wm = (wv & 1) * 64, wn = (wv >> 1) * 64;
  const int lm = lane & 15, quad = lane >> 4;
  const int srow = lane >> 2, scol = (lane & 3) * 8;  // 4 lanes per 32-u16 row

  v4f acc[4][4];
  v4f zero = {0.f, 0.f, 0.f, 0.f};
#pragma unroll
  for (int i = 0; i < 4; ++i)
#pragma unroll
    for (int j = 0; j < 4; ++j) acc[i][j] = zero;

  for (int k0 = 0; k0 < K; k0 += 32) {
#pragma unroll
    for (int c = 0; c < 2; ++c) {
      const int r = wv * 32 + c * 16;  // wave-uniform row base; lane deposits r+srow,scol
      async16(A  + (size_t)(bm0 + r + srow) * K + k0 + scol, &As[r][0]);
      async16(BT + (size_t)(bn0 + r + srow) * K + k0 + scol, &Bs[r][0]);
    }
    __builtin_amdgcn_s_waitcnt(0);
    __syncthreads();
    v8s a[4], b[4];
#pragma unroll
    for (int mt = 0; mt < 4; ++mt) a[mt] = *(const v8s*)&As[wm + mt * 16 + lm][quad * 8];
#pragma unroll
    for (int nt = 0; nt < 4; ++nt) b[nt] = *(const v8s*)&Bs[wn + nt * 16 + lm][quad * 8];
#pragma unroll
    for (int mt = 0; mt < 4; ++mt)
#pragma unroll
      for (int nt = 0; nt < 4; ++nt)
        acc[mt][nt] = __builtin_amdgcn_mfma_f32_16x16x32_bf16(a[mt], b[nt], acc[mt][nt], 0, 0, 0);
    __syncthreads();
  }

  if constexpr (KV_SPLIT) {
    if (bn0 < 768) {
      u16* kp_ = (u16*)Cp;
#pragma unroll
      for (int mt = 0; mt < 4; ++mt)
#pragma unroll
        for (int nt = 0; nt < 4; ++nt) {
          int col = bn0 + wn + nt * 16 + lm;
          float bs = bias[col];
#pragma unroll
          for (int r = 0; r < 4; ++r) {
            int grow = m_off + bm0 + wm + mt * 16 + quad * 4 + r;
            kp_[(size_t)grow * 768 + col] = f2bf(acc[mt][nt][r] + bs);
          }
        }
    } else {
#pragma unroll
      for (int mt = 0; mt < 4; ++mt)
#pragma unroll
        for (int nt = 0; nt < 4; ++nt) {
          int col = bn0 + wn + nt * 16 + lm;
          int cv = col - 768;
          float bs = bias[col];
          int grow0 = m_off + bm0 + wm + mt * 16 + quad * 4;
          int b_ = grow0 >> 12, kvr = grow0 & 4095;
          uint2 o;
          o.x = pack2(acc[mt][nt][0] + bs, acc[mt][nt][1] + bs);
          o.y = pack2(acc[mt][nt][2] + bs, acc[mt][nt][3] + bs);
          *(uint2*)&Vtp[((size_t)(b_ * 768 + cv)) * 4096 + kvr] = o;
        }
    }
  } else {
#pragma unroll
    for (int mt = 0; mt < 4; ++mt)
#pragma unroll
      for (int nt = 0; nt < 4; ++nt)
#pragma unroll
        for (int r = 0; r < 4; ++r) {
          int row = bm0 + wm + mt * 16 + quad * 4 + r;
          int col = bn0 + wn + nt * 16 + lm;
          float v = acc[mt][nt][r] + bias[col];
          if constexpr (OUT_BF16) ((u16*)Cp)[(size_t)row * N + col] = f2bf(v);
          else                    ((float*)Cp)[(size_t)row * N + col] = v;
        }
  }
}

// one wave per block; block = (b, h, 16-q-row slab); streams all 4096 kv rows
__global__ __launch_bounds__(64) void attn_k(
    const u16* __restrict__ qp,  // (B*64, 768) bf16
    const u16* __restrict__ kp,  // (B*4096, 768) bf16
    const u16* __restrict__ vT,  // (B*768, 4096) bf16: row b*768+h*64+d, col kv
    u16* __restrict__ xo)        // (B*64, 768) bf16
{
  __shared__ __align__(16) u16 Ps[16][40];
  const int lane = threadIdx.x & 63, lm = lane & 15, quad = lane >> 4;
  const int blk = blockIdx.x, qb = blk & 3, bh = blk >> 2;
  const int b = bh / NH, h = bh - b * NH;
  const int qr0 = b * NQ + qb * 16;

  const u16* qptr = qp + (size_t)(qr0 + lm) * QD + h * HD + quad * 8;
  v8s aq0 = *(const v8s*)qptr;
  v8s aq1 = *(const v8s*)(qptr + 32);

  const u16* kb = kp + (size_t)b * NKV * QD + h * HD;
  const u16* vb = vT + (size_t)(b * QD + h * HD) * NKV;

  float mst[4], lst[4];
  v4f O[4];
  v4f zero = {0.f, 0.f, 0.f, 0.f};
#pragma unroll
  for (int r = 0; r < 4; ++r) { mst[r] = -INFINITY; lst[r] = 0.f; }
#pragma unroll
  for (int d = 0; d < 4; ++d) O[d] = zero;

  const float scale = 0.125f;

  v8s kf[2][4], vf[2][4];
  auto loadchunk = [&](int j0, int bi) {
    const u16* k0p = kb + (size_t)(j0 + lm) * QD + quad * 8;
    const u16* k1p = kb + (size_t)(j0 + 16 + lm) * QD + quad * 8;
    kf[bi][0] = *(const v8s*)k0p;
    kf[bi][1] = *(const v8s*)(k0p + 32);
    kf[bi][2] = *(const v8s*)k1p;
    kf[bi][3] = *(const v8s*)(k1p + 32);
#pragma unroll
    for (int d = 0; d < 4; ++d)
      vf[bi][d] = *(const v8s*)&vb[(size_t)(d * 16 + lm) * NKV + j0 + quad * 8];
  };
  auto compute = [&](int bi) {
    v4f S0 = zero, S1 = zero;
    S0 = __builtin_amdgcn_mfma_f32_16x16x32_bf16(aq0, kf[bi][0], S0, 0, 0, 0);
    S0 = __builtin_amdgcn_mfma_f32_16x16x32_bf16(aq1, kf[bi][1], S0, 0, 0, 0);
    S1 = __builtin_amdgcn_mfma_f32_16x16x32_bf16(aq0, kf[bi][2], S1, 0, 0, 0);
    S1 = __builtin_amdgcn_mfma_f32_16x16x32_bf16(aq1, kf[bi][3], S1, 0, 0, 0);

    float p0[4], p1[4], rmax[4];
#pragma unroll
    for (int r = 0; r < 4; ++r) {
      p0[r] = S0[r] * scale; p1[r] = S1[r] * scale;
      rmax[r] = fmaxf(p0[r], p1[r]);
    }
#pragma unroll
    for (int off = 1; off <= 8; off <<= 1)
#pragma unroll
      for (int r = 0; r < 4; ++r) rmax[r] = fmaxf(rmax[r], __shfl_xor(rmax[r], off, 64));

    float alpha[4], rsum[4];
#pragma unroll
    for (int r = 0; r < 4; ++r) {
      float mn = fmaxf(mst[r], rmax[r]);
      alpha[r] = __expf(mst[r] - mn);
      p0[r] = __expf(p0[r] - mn);
      p1[r] = __expf(p1[r] - mn);
      mst[r] = mn;
      rsum[r] = p0[r] + p1[r];
    }
#pragma unroll
    for (int off = 1; off <= 8; off <<= 1)
#pragma unroll
      for (int r = 0; r < 4; ++r) rsum[r] += __shfl_xor(rsum[r], off, 64);
#pragma unroll
    for (int r = 0; r < 4; ++r) {
      lst[r] = lst[r] * alpha[r] + rsum[r];
      Ps[quad * 4 + r][lm] = f2bf(p0[r]);
      Ps[quad * 4 + r][16 + lm] = f2bf(p1[r]);
    }
#pragma unroll
    for (int d = 0; d < 4; ++d)
#pragma unroll
      for (int r = 0; r < 4; ++r) O[d][r] *= alpha[r];
    v8s aP = *(const v8s*)&Ps[lm][quad * 8];  // single wave: DS ops in-order
#pragma unroll
    for (int d = 0; d < 4; ++d)
      O[d] = __builtin_amdgcn_mfma_f32_16x16x32_bf16(aP, vf[bi][d], O[d], 0, 0, 0);
  };

  loadchunk(0, 0);
  for (int j0 = 0; j0 < NKV; j0 += 64) {
    loadchunk(j0 + 32, 1);
    compute(0);
    if (j0 + 64 < NKV) loadchunk(j0 + 64, 0);
    compute(1);
  }

#pragma unroll
  for (int r = 0; r < 4; ++r) lst[r] = 1.f / lst[r];
#pragma unroll
  for (int d = 0; d < 4; ++d)
#pragma unroll
    for (int r = 0; r < 4; ++r)
      xo[(size_t)(qr0 + quad * 4 + r) * QD + h * HD + d * 16 + lm] = f2bf(O[d][r] * lst[r]);
}

extern "C" void kernel_launch(void* const* d_in, const int* in_sizes, int n_in,
                              void* d_out, int out_size, void* d_ws, size_t ws_size,
                              hipStream_t stream) {
  const float* query = (const float*)d_in[0];
  const float* kv    = (const float*)d_in[1];
  const float* Wq    = (const float*)d_in[2];
  const float* bq    = (const float*)d_in[3];
  const float* Wk    = (const float*)d_in[4];
  const float* bk    = (const float*)d_in[5];
  const float* Wv    = (const float*)d_in[6];
  const float* bv    = (const float*)d_in[7];
  const float* Wo    = (const float*)d_in[8];
  const float* bo    = (const float*)d_in[9];
  float* out = (float*)d_out;
  char* ws = (char*)d_ws;

  // ws layout (bytes):
  u16*   WkvT = (u16*)(ws);                   // (1536,1024)      3,145,728
  float* bkv  = (float*)(ws + 3145728);       // 1536 f32             6,144
  u16*   WqT  = (u16*)(ws + 3151872);         // (768,768)        1,179,648
  u16*   WoT  = (u16*)(ws + 4331520);         //                  1,179,648
  u16*   qbf  = (u16*)(ws + 5511168);         // (1024,768)       1,572,864
  u16*   qp   = (u16*)(ws + 7084032);         // (1024,768)       1,572,864
  u16*   xov  = (u16*)(ws + 8656896);         // (1024,768)       1,572,864
  u16*   kp   = (u16*)(ws + 10229760);        // (65536,768)    100,663,296
  u16*   vT   = (u16*)(ws + 110893056);       // (16*768,4096)  100,663,296
  u16*   kvbf = (u16*)(ws + 211556352);       // (8192,1024) chunk 16,777,216
  // total: 228,333,568

  prep_wT2<<<dim3(24, 32), 256, 0, stream>>>(Wk, WkvT, KD, QD);
  prep_wT2<<<dim3(24, 32), 256, 0, stream>>>(Wv, WkvT + 768 * 1024, KD, QD);
  prep_wT2<<<dim3(24, 24), 256, 0, stream>>>(Wq, WqT, QD, QD);
  prep_wT2<<<dim3(24, 24), 256, 0, stream>>>(Wo, WoT, QD, QD);
  conv8<<<384, 256, 0, stream>>>(query, qbf, NB * NQ * QD / 8);
  concat_bias<<<6, 256, 0, stream>>>(bk, bv, bkv);

  // q projection
  gemm_a<true, false><<<dim3(6, 8), 256, 0, stream>>>(qbf, WqT, bq, qp, nullptr,
                                                      1024, QD, QD, 0);
  // fused k+v projection, 8 chunks of 8192 rows (convert f32->bf16 then GEMM)
  for (int ch = 0; ch < 8; ++ch) {
    conv8<<<4096, 256, 0, stream>>>(kv + (size_t)ch * 8192 * KD, kvbf, 8192 * KD / 8);
    gemm_a<true, true><<<dim3(12, 64), 256, 0, stream>>>(kvbf, WkvT, bkv, kp, vT,
                                                         8192, 1536, KD, ch * 8192);
  }
  // attention: 1 wave per (b, h, 16-row q slab)
  attn_k<<<NB * NH * 4, 64, 0, stream>>>(qp, kp, vT, xov);
  // output projection -> f32
  gemm_a<false, false><<<dim3(6, 8), 256, 0, stream>>>(xov, WoT, bo, out, nullptr,
                                                       1024, QD, QD, 0);
}

// Round 3
// 971.720 us; speedup vs baseline: 1.1016x; 1.0772x over previous
//
#include <hip/hip_runtime.h>
#include <hip/hip_bf16.h>

typedef unsigned short u16;
typedef unsigned int u32;
typedef short v8s __attribute__((ext_vector_type(8)));
typedef float v4f __attribute__((ext_vector_type(4)));

#define NB 16
#define NQ 64
#define NKV 4096
#define QD 768
#define KD 1024
#define NH 12
#define HD 64

__device__ __forceinline__ u16 f2bf(float f) {
  union { float f; u32 u; } c; c.f = f;
  u32 u = c.u;
  u += 0x7FFFu + ((u >> 16) & 1u);  // round-to-nearest-even
  return (u16)(u >> 16);
}
__device__ __forceinline__ u32 pack2(float a, float b) {
  return (u32)f2bf(a) | ((u32)f2bf(b) << 16);
}

// async 16B global->LDS; lds dest must be wave-uniform base (+lane*16 implicit)
__device__ __forceinline__ void async16(const void* g, void* l) {
  __builtin_amdgcn_global_load_lds(
      (const __attribute__((address_space(1))) void*)g,
      (__attribute__((address_space(3))) void*)l, 16, 0, 0);
}

// two W (K,N) f32 -> WT (N,K) bf16 transposes in one launch (blockIdx.z picks)
__global__ __launch_bounds__(256) void prep_wT_dual(
    const float* __restrict__ W0, const float* __restrict__ W1,
    u16* __restrict__ T0, u16* __restrict__ T1, int K, int N) {
  __shared__ float tile[32][33];
  const float* W = blockIdx.z ? W1 : W0;
  u16* WT = blockIdx.z ? T1 : T0;
  const int n0 = blockIdx.x * 32, k0 = blockIdx.y * 32;
  const int tr = threadIdx.x >> 5, tc = threadIdx.x & 31;
#pragma unroll
  for (int r = tr; r < 32; r += 8) tile[r][tc] = W[(size_t)(k0 + r) * N + n0 + tc];
  __syncthreads();
#pragma unroll
  for (int r = tr; r < 32; r += 8) WT[(size_t)(n0 + r) * K + k0 + tc] = f2bf(tile[tc][r]);
}

// f32 -> bf16, 8 elements/thread
__global__ __launch_bounds__(256) void conv8(const float* __restrict__ s,
                                             u16* __restrict__ d, int n8) {
  int i = blockIdx.x * 256 + threadIdx.x;
  if (i >= n8) return;
  const float4* sp = (const float4*)s + (size_t)i * 2;
  float4 a = sp[0], b = sp[1];
  uint4 o;
  o.x = pack2(a.x, a.y); o.y = pack2(a.z, a.w);
  o.z = pack2(b.x, b.y); o.w = pack2(b.z, b.w);
  ((uint4*)d)[i] = o;
}

__global__ void concat_bias(const float* __restrict__ a, const float* __restrict__ b,
                            float* __restrict__ o) {
  int i = blockIdx.x * 256 + threadIdx.x;
  if (i < 768) o[i] = a[i];
  else if (i < 1536) o[i] = b[i - 768];
}

// C = A[M,K](bf16) @ BT[N,K]^T + bias.
// KV_SPLIT: cols<768 -> kp[grow*768+col]; cols>=768 -> vT[(b*768+cv)*4096+kvr] (transposed)
template<bool OUT_BF16, bool KV_SPLIT>
__global__ __launch_bounds__(256) void gemm_a(
    const u16* __restrict__ A, const u16* __restrict__ BT,
    const float* __restrict__ bias, void* __restrict__ Cp, u16* __restrict__ Vtp,
    int M, int N, int K)
{
  __shared__ __align__(16) u16 As[128][32];  // unpadded: required by global_load_lds
  __shared__ __align__(16) u16 Bs[128][32];
  const int bn0 = blockIdx.x * 128, bm0 = blockIdx.y * 128;
  const int t = threadIdx.x, lane = t & 63, wv = t >> 6;
  const int wm = (wv & 1) * 64, wn = (wv >> 1) * 64;
  const int lm = lane & 15, quad = lane >> 4;
  const int srow = lane >> 2, scol = (lane & 3) * 8;  // 4 lanes per 32-u16 row

  v4f acc[4][4];
  v4f zero = {0.f, 0.f, 0.f, 0.f};
#pragma unroll
  for (int i = 0; i < 4; ++i)
#pragma unroll
    for (int j = 0; j < 4; ++j) acc[i][j] = zero;

  for (int k0 = 0; k0 < K; k0 += 32) {
#pragma unroll
    for (int c = 0; c < 2; ++c) {
      const int r = wv * 32 + c * 16;  // wave-uniform base; lane deposits r+srow,scol
      async16(A  + (size_t)(bm0 + r + srow) * K + k0 + scol, &As[r][0]);
      async16(BT + (size_t)(bn0 + r + srow) * K + k0 + scol, &Bs[r][0]);
    }
    __builtin_amdgcn_s_waitcnt(0);
    __syncthreads();
    v8s a[4], b[4];
#pragma unroll
    for (int mt = 0; mt < 4; ++mt) a[mt] = *(const v8s*)&As[wm + mt * 16 + lm][quad * 8];
#pragma unroll
    for (int nt = 0; nt < 4; ++nt) b[nt] = *(const v8s*)&Bs[wn + nt * 16 + lm][quad * 8];
#pragma unroll
    for (int mt = 0; mt < 4; ++mt)
#pragma unroll
      for (int nt = 0; nt < 4; ++nt)
        acc[mt][nt] = __builtin_amdgcn_mfma_f32_16x16x32_bf16(a[mt], b[nt], acc[mt][nt], 0, 0, 0);
    __syncthreads();
  }

  if constexpr (KV_SPLIT) {
    if (bn0 < 768) {
      u16* kp_ = (u16*)Cp;
#pragma unroll
      for (int mt = 0; mt < 4; ++mt)
#pragma unroll
        for (int nt = 0; nt < 4; ++nt) {
          int col = bn0 + wn + nt * 16 + lm;
          float bs = bias[col];
#pragma unroll
          for (int r = 0; r < 4; ++r) {
            int grow = bm0 + wm + mt * 16 + quad * 4 + r;
            kp_[(size_t)grow * 768 + col] = f2bf(acc[mt][nt][r] + bs);
          }
        }
    } else {
#pragma unroll
      for (int mt = 0; mt < 4; ++mt)
#pragma unroll
        for (int nt = 0; nt < 4; ++nt) {
          int col = bn0 + wn + nt * 16 + lm;
          int cv = col - 768;
          float bs = bias[col];
          int grow0 = bm0 + wm + mt * 16 + quad * 4;
          int b_ = grow0 >> 12, kvr = grow0 & 4095;
          uint2 o;
          o.x = pack2(acc[mt][nt][0] + bs, acc[mt][nt][1] + bs);
          o.y = pack2(acc[mt][nt][2] + bs, acc[mt][nt][3] + bs);
          *(uint2*)&Vtp[((size_t)(b_ * 768 + cv)) * 4096 + kvr] = o;
        }
    }
  } else {
#pragma unroll
    for (int mt = 0; mt < 4; ++mt)
#pragma unroll
      for (int nt = 0; nt < 4; ++nt)
#pragma unroll
        for (int r = 0; r < 4; ++r) {
          int row = bm0 + wm + mt * 16 + quad * 4 + r;
          int col = bn0 + wn + nt * 16 + lm;
          float v = acc[mt][nt][r] + bias[col];
          if constexpr (OUT_BF16) ((u16*)Cp)[(size_t)row * N + col] = f2bf(v);
          else                    ((float*)Cp)[(size_t)row * N + col] = v;
        }
  }
}

// block = (b, h, 16-row q slab); 4 waves, wave w covers kv rows [w*1024, w*1024+1024)
// partial (m,l,O) combined across waves in LDS at the end.
__global__ __launch_bounds__(256) void attn_k(
    const u16* __restrict__ qp,  // (B*64, 768) bf16
    const u16* __restrict__ kp,  // (B*4096, 768) bf16
    const u16* __restrict__ vT,  // (B*768, 4096) bf16: row b*768+h*64+d, col kv
    u16* __restrict__ xo)        // (B*64, 768) bf16
{
  __shared__ __align__(16) u16 Ps[4][16][40];
  __shared__ float Mw[4][16], Lw[4][16];
  __shared__ float Os[4][16][64];
  const int lane = threadIdx.x & 63, w = threadIdx.x >> 6;
  const int lm = lane & 15, quad = lane >> 4;
  const int blk = blockIdx.x, slab = blk & 3, bh = blk >> 2;
  const int b = bh / NH, h = bh - b * NH;
  const int qr0 = b * NQ + slab * 16;

  const u16* qptr = qp + (size_t)(qr0 + lm) * QD + h * HD + quad * 8;
  v8s aq0 = *(const v8s*)qptr;
  v8s aq1 = *(const v8s*)(qptr + 32);

  const u16* kb = kp + (size_t)b * NKV * QD + h * HD;
  const u16* vb = vT + (size_t)(b * QD + h * HD) * NKV;

  float mst[4], lst[4];
  v4f O[4];
  v4f zero = {0.f, 0.f, 0.f, 0.f};
#pragma unroll
  for (int r = 0; r < 4; ++r) { mst[r] = -INFINITY; lst[r] = 0.f; }
#pragma unroll
  for (int d = 0; d < 4; ++d) O[d] = zero;

  const float scale = 0.125f;

  v8s kf[2][4], vf[2][4];
  auto loadchunk = [&](int j0, int bi) {
    const u16* k0p = kb + (size_t)(j0 + lm) * QD + quad * 8;
    const u16* k1p = kb + (size_t)(j0 + 16 + lm) * QD + quad * 8;
    kf[bi][0] = *(const v8s*)k0p;
    kf[bi][1] = *(const v8s*)(k0p + 32);
    kf[bi][2] = *(const v8s*)k1p;
    kf[bi][3] = *(const v8s*)(k1p + 32);
#pragma unroll
    for (int d = 0; d < 4; ++d)
      vf[bi][d] = *(const v8s*)&vb[(size_t)(d * 16 + lm) * NKV + j0 + quad * 8];
  };
  auto compute = [&](int bi) {
    v4f S0 = zero, S1 = zero;
    S0 = __builtin_amdgcn_mfma_f32_16x16x32_bf16(aq0, kf[bi][0], S0, 0, 0, 0);
    S0 = __builtin_amdgcn_mfma_f32_16x16x32_bf16(aq1, kf[bi][1], S0, 0, 0, 0);
    S1 = __builtin_amdgcn_mfma_f32_16x16x32_bf16(aq0, kf[bi][2], S1, 0, 0, 0);
    S1 = __builtin_amdgcn_mfma_f32_16x16x32_bf16(aq1, kf[bi][3], S1, 0, 0, 0);

    float p0[4], p1[4], rmax[4];
#pragma unroll
    for (int r = 0; r < 4; ++r) {
      p0[r] = S0[r] * scale; p1[r] = S1[r] * scale;
      rmax[r] = fmaxf(p0[r], p1[r]);
    }
#pragma unroll
    for (int off = 1; off <= 8; off <<= 1)
#pragma unroll
      for (int r = 0; r < 4; ++r) rmax[r] = fmaxf(rmax[r], __shfl_xor(rmax[r], off, 64));

    float alpha[4], rsum[4];
#pragma unroll
    for (int r = 0; r < 4; ++r) {
      float mn = fmaxf(mst[r], rmax[r]);
      alpha[r] = __expf(mst[r] - mn);
      p0[r] = __expf(p0[r] - mn);
      p1[r] = __expf(p1[r] - mn);
      mst[r] = mn;
      rsum[r] = p0[r] + p1[r];
    }
#pragma unroll
    for (int off = 1; off <= 8; off <<= 1)
#pragma unroll
      for (int r = 0; r < 4; ++r) rsum[r] += __shfl_xor(rsum[r], off, 64);
#pragma unroll
    for (int r = 0; r < 4; ++r) {
      lst[r] = lst[r] * alpha[r] + rsum[r];
      Ps[w][quad * 4 + r][lm] = f2bf(p0[r]);
      Ps[w][quad * 4 + r][16 + lm] = f2bf(p1[r]);
    }
#pragma unroll
    for (int d = 0; d < 4; ++d)
#pragma unroll
      for (int r = 0; r < 4; ++r) O[d][r] *= alpha[r];
    v8s aP = *(const v8s*)&Ps[w][lm][quad * 8];  // single-wave DS: in-order
#pragma unroll
    for (int d = 0; d < 4; ++d)
      O[d] = __builtin_amdgcn_mfma_f32_16x16x32_bf16(aP, vf[bi][d], O[d], 0, 0, 0);
  };

  const int base = w * 1024;
  loadchunk(base, 0);
  for (int j0 = base; j0 < base + 1024; j0 += 64) {
    loadchunk(j0 + 32, 1);
    compute(0);
    if (j0 + 64 < base + 1024) loadchunk(j0 + 64, 0);
    compute(1);
  }

  // cross-wave online-softmax combine
  if (lm == 0) {
#pragma unroll
    for (int r = 0; r < 4; ++r) {
      Mw[w][quad * 4 + r] = mst[r];
      Lw[w][quad * 4 + r] = lst[r];
    }
  }
  __syncthreads();
#pragma unroll
  for (int r = 0; r < 4; ++r) {
    int row = quad * 4 + r;
    float M = fmaxf(fmaxf(Mw[0][row], Mw[1][row]), fmaxf(Mw[2][row], Mw[3][row]));
    float sc = __expf(mst[r] - M);
#pragma unroll
    for (int d = 0; d < 4; ++d) Os[w][row][d * 16 + lm] = O[d][r] * sc;
  }
  __syncthreads();
#pragma unroll
  for (int i = 0; i < 4; ++i) {
    int row = w * 4 + i;
    float M = fmaxf(fmaxf(Mw[0][row], Mw[1][row]), fmaxf(Mw[2][row], Mw[3][row]));
    float L = Lw[0][row] * __expf(Mw[0][row] - M) + Lw[1][row] * __expf(Mw[1][row] - M)
            + Lw[2][row] * __expf(Mw[2][row] - M) + Lw[3][row] * __expf(Mw[3][row] - M);
    float o = Os[0][row][lane] + Os[1][row][lane] + Os[2][row][lane] + Os[3][row][lane];
    xo[(size_t)(qr0 + row) * QD + h * HD + lane] = f2bf(o / L);
  }
}

extern "C" void kernel_launch(void* const* d_in, const int* in_sizes, int n_in,
                              void* d_out, int out_size, void* d_ws, size_t ws_size,
                              hipStream_t stream) {
  const float* query = (const float*)d_in[0];
  const float* kv    = (const float*)d_in[1];
  const float* Wq    = (const float*)d_in[2];
  const float* bq    = (const float*)d_in[3];
  const float* Wk    = (const float*)d_in[4];
  const float* bk    = (const float*)d_in[5];
  const float* Wv    = (const float*)d_in[6];
  const float* bv    = (const float*)d_in[7];
  const float* Wo    = (const float*)d_in[8];
  const float* bo    = (const float*)d_in[9];
  float* out = (float*)d_out;
  char* ws = (char*)d_ws;

  // ws layout (bytes); ws_size ~1 GiB per harness fill, total used: 345,774,080
  u16*   WkvT = (u16*)(ws);                   // (1536,1024)      3,145,728
  float* bkv  = (float*)(ws + 3145728);       // 1536 f32             6,144
  u16*   WqT  = (u16*)(ws + 3151872);         // (768,768)        1,179,648
  u16*   WoT  = (u16*)(ws + 4331520);         //                  1,179,648
  u16*   qbf  = (u16*)(ws + 5511168);         // (1024,768)       1,572,864
  u16*   qp   = (u16*)(ws + 7084032);         // (1024,768)       1,572,864
  u16*   xov  = (u16*)(ws + 8656896);         // (1024,768)       1,572,864
  u16*   kp   = (u16*)(ws + 10229760);        // (65536,768)    100,663,296
  u16*   vT   = (u16*)(ws + 110893056);       // (16*768,4096)  100,663,296
  u16*   kvbf = (u16*)(ws + 211556352);       // (65536,1024)   134,217,728

  // weight transposes (Wk+Wv in one launch; Wq+Wo in one launch)
  prep_wT_dual<<<dim3(24, 32, 2), 256, 0, stream>>>(Wk, Wv, WkvT, WkvT + 768 * 1024, KD, QD);
  prep_wT_dual<<<dim3(24, 24, 2), 256, 0, stream>>>(Wq, Wo, WqT, WoT, QD, QD);
  concat_bias<<<6, 256, 0, stream>>>(bk, bv, bkv);
  // full kv f32 -> bf16 (one pass)
  conv8<<<32768, 256, 0, stream>>>(kv, kvbf, NB * NKV * KD / 8);
  // fused k+v projection: (65536,1024) @ (1024,1536) -> kp + transposed vT
  gemm_a<true, true><<<dim3(12, 512), 256, 0, stream>>>(kvbf, WkvT, bkv, kp, vT,
                                                        65536, 1536, KD);
  // q conversion + projection
  conv8<<<384, 256, 0, stream>>>(query, qbf, NB * NQ * QD / 8);
  gemm_a<true, false><<<dim3(6, 8), 256, 0, stream>>>(qbf, WqT, bq, qp, nullptr,
                                                      1024, QD, QD);
  // attention: block=(b,h,slab), 4 waves kv-split + LDS combine
  attn_k<<<NB * NH * 4, 256, 0, stream>>>(qp, kp, vT, xov);
  // output projection -> f32
  gemm_a<false, false><<<dim3(6, 8), 256, 0, stream>>>(xov, WoT, bo, out, nullptr,
                                                       1024, QD, QD);
}

// Round 4
// 952.873 us; speedup vs baseline: 1.1234x; 1.0198x over previous
//
#include <hip/hip_runtime.h>
#include <hip/hip_bf16.h>

typedef unsigned short u16;
typedef unsigned int u32;
typedef short v8s __attribute__((ext_vector_type(8)));
typedef float v4f __attribute__((ext_vector_type(4)));

#define NB 16
#define NQ 64
#define NKV 4096
#define QD 768
#define KD 1024
#define NH 12
#define HD 64

__device__ __forceinline__ u16 f2bf(float f) {
  union { float f; u32 u; } c; c.f = f;
  u32 u = c.u;
  u += 0x7FFFu + ((u >> 16) & 1u);  // round-to-nearest-even
  return (u16)(u >> 16);
}
__device__ __forceinline__ u32 pack2(float a, float b) {
  return (u32)f2bf(a) | ((u32)f2bf(b) << 16);
}

// async 16B global->LDS; lds dest = wave-uniform base + lane*16
__device__ __forceinline__ void async16(const void* g, void* l) {
  __builtin_amdgcn_global_load_lds(
      (const __attribute__((address_space(1))) void*)g,
      (__attribute__((address_space(3))) void*)l, 16, 0, 0);
}

// two W (K,N) f32 -> WT (N,K) bf16 transposes in one launch (blockIdx.z picks)
__global__ __launch_bounds__(256) void prep_wT_dual(
    const float* __restrict__ W0, const float* __restrict__ W1,
    u16* __restrict__ T0, u16* __restrict__ T1, int K, int N) {
  __shared__ float tile[32][33];
  const float* W = blockIdx.z ? W1 : W0;
  u16* WT = blockIdx.z ? T1 : T0;
  const int n0 = blockIdx.x * 32, k0 = blockIdx.y * 32;
  const int tr = threadIdx.x >> 5, tc = threadIdx.x & 31;
#pragma unroll
  for (int r = tr; r < 32; r += 8) tile[r][tc] = W[(size_t)(k0 + r) * N + n0 + tc];
  __syncthreads();
#pragma unroll
  for (int r = tr; r < 32; r += 8) WT[(size_t)(n0 + r) * K + k0 + tc] = f2bf(tile[tc][r]);
}

// f32 -> bf16, 8 elements/thread
__global__ __launch_bounds__(256) void conv8(const float* __restrict__ s,
                                             u16* __restrict__ d, int n8) {
  int i = blockIdx.x * 256 + threadIdx.x;
  if (i >= n8) return;
  const float4* sp = (const float4*)s + (size_t)i * 2;
  float4 a = sp[0], b = sp[1];
  uint4 o;
  o.x = pack2(a.x, a.y); o.y = pack2(a.z, a.w);
  o.z = pack2(b.x, b.y); o.w = pack2(b.z, b.w);
  ((uint4*)d)[i] = o;
}

__global__ void concat_bias(const float* __restrict__ a, const float* __restrict__ b,
                            float* __restrict__ o) {
  int i = blockIdx.x * 256 + threadIdx.x;
  if (i < 768) o[i] = a[i];
  else if (i < 1536) o[i] = b[i - 768];
}

// C = A[M,K](bf16) @ BT[N,K]^T + bias.
// LDS layout is XOR-swizzled: global chunk (c ^ ((row>>1)&3)) is stored at chunk c
// so MFMA fragment reads are 2-way-bank-aliased only (free) despite unpadded rows.
// KV_SPLIT: cols<768 -> kp[grow*768+col]; cols>=768 -> vT[(b*768+cv)*4096+kvr] (transposed)
template<bool OUT_BF16, bool KV_SPLIT>
__global__ __launch_bounds__(256) void gemm_a(
    const u16* __restrict__ A, const u16* __restrict__ BT,
    const float* __restrict__ bias, void* __restrict__ Cp, u16* __restrict__ Vtp,
    int M, int N, int K)
{
  __shared__ __align__(16) u16 As[128][32];  // unpadded (global_load_lds), swizzled
  __shared__ __align__(16) u16 Bs[128][32];
  const int bn0 = blockIdx.x * 128, bm0 = blockIdx.y * 128;
  const int t = threadIdx.x, lane = t & 63, wv = t >> 6;
  const int wm = (wv & 1) * 64, wn = (wv >> 1) * 64;
  const int lm = lane & 15, quad = lane >> 4;
  const int srow = lane >> 2;                              // 4 lanes per 32-u16 row
  const int sc = (((lane & 3) ^ ((srow >> 1) & 3)) * 8);   // swizzled source chunk

  // staging pointers, strength-reduced (advance 32 elems per K-step)
  const int r0 = wv * 32, r1 = wv * 32 + 16;
  const u16* aP0 = A  + (size_t)(bm0 + r0 + srow) * K + sc;
  const u16* aP1 = A  + (size_t)(bm0 + r1 + srow) * K + sc;
  const u16* bP0 = BT + (size_t)(bn0 + r0 + srow) * K + sc;
  const u16* bP1 = BT + (size_t)(bn0 + r1 + srow) * K + sc;

  const int swz = (lm >> 1) & 3;  // reader swizzle (row-base invariant: tiles 16-aligned)

  v4f acc[4][4];
  v4f zero = {0.f, 0.f, 0.f, 0.f};
#pragma unroll
  for (int i = 0; i < 4; ++i)
#pragma unroll
    for (int j = 0; j < 4; ++j) acc[i][j] = zero;

  for (int k0 = 0; k0 < K; k0 += 32) {
    async16(aP0, &As[r0][0]);
    async16(aP1, &As[r1][0]);
    async16(bP0, &Bs[r0][0]);
    async16(bP1, &Bs[r1][0]);
    aP0 += 32; aP1 += 32; bP0 += 32; bP1 += 32;
    __builtin_amdgcn_s_waitcnt(0);
    __syncthreads();
    v8s a[4], b[4];
#pragma unroll
    for (int mt = 0; mt < 4; ++mt)
      a[mt] = *(const v8s*)&As[wm + mt * 16 + lm][(quad ^ swz) * 8];
#pragma unroll
    for (int nt = 0; nt < 4; ++nt)
      b[nt] = *(const v8s*)&Bs[wn + nt * 16 + lm][(quad ^ swz) * 8];
#pragma unroll
    for (int mt = 0; mt < 4; ++mt)
#pragma unroll
      for (int nt = 0; nt < 4; ++nt)
        acc[mt][nt] = __builtin_amdgcn_mfma_f32_16x16x32_bf16(a[mt], b[nt], acc[mt][nt], 0, 0, 0);
    __syncthreads();
  }

  if constexpr (KV_SPLIT) {
    if (bn0 < 768) {
      u16* kp_ = (u16*)Cp;
#pragma unroll
      for (int mt = 0; mt < 4; ++mt)
#pragma unroll
        for (int nt = 0; nt < 4; ++nt) {
          int col = bn0 + wn + nt * 16 + lm;
          float bs = bias[col];
#pragma unroll
          for (int r = 0; r < 4; ++r) {
            int grow = bm0 + wm + mt * 16 + quad * 4 + r;
            kp_[(size_t)grow * 768 + col] = f2bf(acc[mt][nt][r] + bs);
          }
        }
    } else {
#pragma unroll
      for (int mt = 0; mt < 4; ++mt)
#pragma unroll
        for (int nt = 0; nt < 4; ++nt) {
          int col = bn0 + wn + nt * 16 + lm;
          int cv = col - 768;
          float bs = bias[col];
          int grow0 = bm0 + wm + mt * 16 + quad * 4;
          int b_ = grow0 >> 12, kvr = grow0 & 4095;
          uint2 o;
          o.x = pack2(acc[mt][nt][0] + bs, acc[mt][nt][1] + bs);
          o.y = pack2(acc[mt][nt][2] + bs, acc[mt][nt][3] + bs);
          *(uint2*)&Vtp[((size_t)(b_ * 768 + cv)) * 4096 + kvr] = o;
        }
    }
  } else {
#pragma unroll
    for (int mt = 0; mt < 4; ++mt)
#pragma unroll
      for (int nt = 0; nt < 4; ++nt)
#pragma unroll
        for (int r = 0; r < 4; ++r) {
          int row = bm0 + wm + mt * 16 + quad * 4 + r;
          int col = bn0 + wn + nt * 16 + lm;
          float v = acc[mt][nt][r] + bias[col];
          if constexpr (OUT_BF16) ((u16*)Cp)[(size_t)row * N + col] = f2bf(v);
          else                    ((float*)Cp)[(size_t)row * N + col] = v;
        }
  }
}

// block = (b, h, 16-row q slab); 4 waves, wave w covers kv rows [w*1024, w*1024+1024)
// partial (m,l,O) combined across waves in LDS at the end.
__global__ __launch_bounds__(256) void attn_k(
    const u16* __restrict__ qp,  // (B*64, 768) bf16
    const u16* __restrict__ kp,  // (B*4096, 768) bf16
    const u16* __restrict__ vT,  // (B*768, 4096) bf16: row b*768+h*64+d, col kv
    u16* __restrict__ xo)        // (B*64, 768) bf16
{
  __shared__ __align__(16) u16 Ps[4][16][40];
  __shared__ float Mw[4][16], Lw[4][16];
  __shared__ float Os[4][16][64];
  const int lane = threadIdx.x & 63, w = threadIdx.x >> 6;
  const int lm = lane & 15, quad = lane >> 4;
  const int blk = blockIdx.x, slab = blk & 3, bh = blk >> 2;
  const int b = bh / NH, h = bh - b * NH;
  const int qr0 = b * NQ + slab * 16;

  const u16* qptr = qp + (size_t)(qr0 + lm) * QD + h * HD + quad * 8;
  v8s aq0 = *(const v8s*)qptr;
  v8s aq1 = *(const v8s*)(qptr + 32);

  const u16* kb = kp + (size_t)b * NKV * QD + h * HD;
  const u16* vb = vT + (size_t)(b * QD + h * HD) * NKV;

  float mst[4], lst[4];
  v4f O[4];
  v4f zero = {0.f, 0.f, 0.f, 0.f};
#pragma unroll
  for (int r = 0; r < 4; ++r) { mst[r] = -INFINITY; lst[r] = 0.f; }
#pragma unroll
  for (int d = 0; d < 4; ++d) O[d] = zero;

  const float scale = 0.125f;

  v8s kf[2][4], vf[2][4];
  auto loadchunk = [&](int j0, int bi) {
    const u16* k0p = kb + (size_t)(j0 + lm) * QD + quad * 8;
    const u16* k1p = kb + (size_t)(j0 + 16 + lm) * QD + quad * 8;
    kf[bi][0] = *(const v8s*)k0p;
    kf[bi][1] = *(const v8s*)(k0p + 32);
    kf[bi][2] = *(const v8s*)k1p;
    kf[bi][3] = *(const v8s*)(k1p + 32);
#pragma unroll
    for (int d = 0; d < 4; ++d)
      vf[bi][d] = *(const v8s*)&vb[(size_t)(d * 16 + lm) * NKV + j0 + quad * 8];
  };
  auto compute = [&](int bi) {
    v4f S0 = zero, S1 = zero;
    S0 = __builtin_amdgcn_mfma_f32_16x16x32_bf16(aq0, kf[bi][0], S0, 0, 0, 0);
    S0 = __builtin_amdgcn_mfma_f32_16x16x32_bf16(aq1, kf[bi][1], S0, 0, 0, 0);
    S1 = __builtin_amdgcn_mfma_f32_16x16x32_bf16(aq0, kf[bi][2], S1, 0, 0, 0);
    S1 = __builtin_amdgcn_mfma_f32_16x16x32_bf16(aq1, kf[bi][3], S1, 0, 0, 0);

    float p0[4], p1[4], rmax[4];
#pragma unroll
    for (int r = 0; r < 4; ++r) {
      p0[r] = S0[r] * scale; p1[r] = S1[r] * scale;
      rmax[r] = fmaxf(p0[r], p1[r]);
    }
#pragma unroll
    for (int off = 1; off <= 8; off <<= 1)
#pragma unroll
      for (int r = 0; r < 4; ++r) rmax[r] = fmaxf(rmax[r], __shfl_xor(rmax[r], off, 64));

    float alpha[4], rsum[4];
#pragma unroll
    for (int r = 0; r < 4; ++r) {
      float mn = fmaxf(mst[r], rmax[r]);
      alpha[r] = __expf(mst[r] - mn);
      p0[r] = __expf(p0[r] - mn);
      p1[r] = __expf(p1[r] - mn);
      mst[r] = mn;
      rsum[r] = p0[r] + p1[r];
    }
#pragma unroll
    for (int off = 1; off <= 8; off <<= 1)
#pragma unroll
      for (int r = 0; r < 4; ++r) rsum[r] += __shfl_xor(rsum[r], off, 64);
#pragma unroll
    for (int r = 0; r < 4; ++r) {
      lst[r] = lst[r] * alpha[r] + rsum[r];
      Ps[w][quad * 4 + r][lm] = f2bf(p0[r]);
      Ps[w][quad * 4 + r][16 + lm] = f2bf(p1[r]);
    }
#pragma unroll
    for (int d = 0; d < 4; ++d)
#pragma unroll
      for (int r = 0; r < 4; ++r) O[d][r] *= alpha[r];
    v8s aP = *(const v8s*)&Ps[w][lm][quad * 8];  // single-wave DS: in-order
#pragma unroll
    for (int d = 0; d < 4; ++d)
      O[d] = __builtin_amdgcn_mfma_f32_16x16x32_bf16(aP, vf[bi][d], O[d], 0, 0, 0);
  };

  const int base = w * 1024;
  loadchunk(base, 0);
  for (int j0 = base; j0 < base + 1024; j0 += 64) {
    loadchunk(j0 + 32, 1);
    compute(0);
    if (j0 + 64 < base + 1024) loadchunk(j0 + 64, 0);
    compute(1);
  }

  // cross-wave online-softmax combine
  if (lm == 0) {
#pragma unroll
    for (int r = 0; r < 4; ++r) {
      Mw[w][quad * 4 + r] = mst[r];
      Lw[w][quad * 4 + r] = lst[r];
    }
  }
  __syncthreads();
#pragma unroll
  for (int r = 0; r < 4; ++r) {
    int row = quad * 4 + r;
    float M = fmaxf(fmaxf(Mw[0][row], Mw[1][row]), fmaxf(Mw[2][row], Mw[3][row]));
    float sc = __expf(mst[r] - M);
#pragma unroll
    for (int d = 0; d < 4; ++d) Os[w][row][d * 16 + lm] = O[d][r] * sc;
  }
  __syncthreads();
#pragma unroll
  for (int i = 0; i < 4; ++i) {
    int row = w * 4 + i;
    float M = fmaxf(fmaxf(Mw[0][row], Mw[1][row]), fmaxf(Mw[2][row], Mw[3][row]));
    float L = Lw[0][row] * __expf(Mw[0][row] - M) + Lw[1][row] * __expf(Mw[1][row] - M)
            + Lw[2][row] * __expf(Mw[2][row] - M) + Lw[3][row] * __expf(Mw[3][row] - M);
    float o = Os[0][row][lane] + Os[1][row][lane] + Os[2][row][lane] + Os[3][row][lane];
    xo[(size_t)(qr0 + row) * QD + h * HD + lane] = f2bf(o / L);
  }
}

extern "C" void kernel_launch(void* const* d_in, const int* in_sizes, int n_in,
                              void* d_out, int out_size, void* d_ws, size_t ws_size,
                              hipStream_t stream) {
  const float* query = (const float*)d_in[0];
  const float* kv    = (const float*)d_in[1];
  const float* Wq    = (const float*)d_in[2];
  const float* bq    = (const float*)d_in[3];
  const float* Wk    = (const float*)d_in[4];
  const float* bk    = (const float*)d_in[5];
  const float* Wv    = (const float*)d_in[6];
  const float* bv    = (const float*)d_in[7];
  const float* Wo    = (const float*)d_in[8];
  const float* bo    = (const float*)d_in[9];
  float* out = (float*)d_out;
  char* ws = (char*)d_ws;

  // ws layout (bytes); total used: 345,774,080
  u16*   WkvT = (u16*)(ws);                   // (1536,1024)      3,145,728
  float* bkv  = (float*)(ws + 3145728);       // 1536 f32             6,144
  u16*   WqT  = (u16*)(ws + 3151872);         // (768,768)        1,179,648
  u16*   WoT  = (u16*)(ws + 4331520);         //                  1,179,648
  u16*   qbf  = (u16*)(ws + 5511168);         // (1024,768)       1,572,864
  u16*   qp   = (u16*)(ws + 7084032);         // (1024,768)       1,572,864
  u16*   xov  = (u16*)(ws + 8656896);         // (1024,768)       1,572,864
  u16*   kp   = (u16*)(ws + 10229760);        // (65536,768)    100,663,296
  u16*   vT   = (u16*)(ws + 110893056);       // (16*768,4096)  100,663,296
  u16*   kvbf = (u16*)(ws + 211556352);       // (65536,1024)   134,217,728

  prep_wT_dual<<<dim3(24, 32, 2), 256, 0, stream>>>(Wk, Wv, WkvT, WkvT + 768 * 1024, KD, QD);
  prep_wT_dual<<<dim3(24, 24, 2), 256, 0, stream>>>(Wq, Wo, WqT, WoT, QD, QD);
  concat_bias<<<6, 256, 0, stream>>>(bk, bv, bkv);
  // full kv f32 -> bf16 (one pass)
  conv8<<<32768, 256, 0, stream>>>(kv, kvbf, NB * NKV * KD / 8);
  // fused k+v projection: (65536,1024) @ (1024,1536) -> kp + transposed vT
  gemm_a<true, true><<<dim3(12, 512), 256, 0, stream>>>(kvbf, WkvT, bkv, kp, vT,
                                                        65536, 1536, KD);
  // q conversion + projection
  conv8<<<384, 256, 0, stream>>>(query, qbf, NB * NQ * QD / 8);
  gemm_a<true, false><<<dim3(6, 8), 256, 0, stream>>>(qbf, WqT, bq, qp, nullptr,
                                                      1024, QD, QD);
  // attention: block=(b,h,slab), 4 waves kv-split + LDS combine
  attn_k<<<NB * NH * 4, 256, 0, stream>>>(qp, kp, vT, xov);
  // output projection -> f32
  gemm_a<false, false><<<dim3(6, 8), 256, 0, stream>>>(xov, WoT, bo, out, nullptr,
                                                       1024, QD, QD);
}